// Round 13
// baseline (630.580 us; speedup 1.0000x reference)
//
#include <hip/hip_runtime.h>
#include <hip/hip_bf16.h>

// ScaledDotAttention: B=4, H=16, S=2048, D=64, fp32 in/out, int mask (nonzero = masked out).
// R13: kv-split x2 for TLP (8192 waves, 5/SIMD via __launch_bounds__(128,5)): block =
//      2 waves on same 32 q-rows, each wave one kv-half (traffic-neutral split), partials
//      combined once through LDS (static-max softmax -> plain add). XCD-swizzled grid
//      (8 contiguous bh per XCD -> K/V fits per-XCD L2). Loop body = R12 verbatim:
//      all-register K/V from pre-relayouted f16 ws, 32x32x16 f16 MFMA, permlane
//      P-exchange, packed-bit mask + 2-op mzero, fdot2 rowsum, log2-domain softmax.

#define SEQ   2048
#define DK    64
#define NB_   4
#define NBH   64
#define KVB   64
#define NT    (SEQ / KVB)

// ws layout: [0,2MB) packed mask | [2MB,18MB) K f16 chunks | [18MB,34MB) V^T f16 chunks
#define MASKH_WORDS ((size_t)NB_ * SEQ * 64)
#define WSK_OFF ((size_t)2 * 1024 * 1024)
#define WSV_OFF ((size_t)18 * 1024 * 1024)
#define WS_NEED ((size_t)34 * 1024 * 1024)

typedef float    f32x16 __attribute__((ext_vector_type(16)));
typedef _Float16 f16x8  __attribute__((ext_vector_type(8)));
typedef _Float16 f16x2v __attribute__((ext_vector_type(2)));

#define QSCALE 0.18033688011112042f   // log2(e)/sqrt(64): scores in log2 domain

#if __has_builtin(__builtin_amdgcn_exp2f)
#define EXP2F(x) __builtin_amdgcn_exp2f(x)
#else
__device__ __forceinline__ float EXP2F(float x) {
  float r;
  asm("v_exp_f32 %0, %1\n\ts_nop 1" : "=v"(r) : "v"(x));
  return r;
}
#endif

__device__ __forceinline__ unsigned pkrtz(float lo, float hi) {
  auto v = __builtin_amdgcn_cvt_pkrtz(lo, hi);
  return __builtin_bit_cast(unsigned, v);
}

// branchless mask-zero: keep v if bit idx of mw is 0 else +0.0f
__device__ __forceinline__ float mzero(float v, unsigned mw, int idx) {
  int s = ((int)(mw << (31 - idx))) >> 31;   // 0 or -1
  unsigned r = __builtin_bit_cast(unsigned, v) & ~(unsigned)s;
  return __builtin_bit_cast(float, r);
}

__device__ __forceinline__ void halfswap(unsigned a, unsigned b,
                                         unsigned& out_lo, unsigned& out_hi, int hiL) {
#if __has_builtin(__builtin_amdgcn_permlane32_swap)
  auto r = __builtin_amdgcn_permlane32_swap(a, b, false, false);
  out_lo = r[0];
  out_hi = r[1];
#else
  unsigned ax = __shfl_xor(a, 32), bx = __shfl_xor(b, 32);
  out_lo = hiL ? bx : a;
  out_hi = hiL ? b : ax;
#endif
}

// ---- ONE merged pre-kernel (packed mask bits + K/V f16 relayout) ------------
__global__ __launch_bounds__(256) void pre_all(
    const int* __restrict__ M, const float* __restrict__ K,
    const float* __restrict__ V, unsigned* __restrict__ Mh,
    _Float16* __restrict__ wsK, _Float16* __restrict__ wsV) {
  const int blk = blockIdx.x;
  if (blk < 2048) {
    int t  = blk * 256 + threadIdx.x;
    int hi = t & 1, T = (t >> 1) & 31, q = (t >> 6) & 2047, b = t >> 17;
    const int* src = M + ((size_t)b * SEQ + q) * SEQ + T * 64 + 4 * hi;
    unsigned bits = 0;
#pragma unroll
    for (int kvb = 0; kvb < 2; ++kvb)
#pragma unroll
      for (int m = 0; m < 4; ++m) {
        int4 v = *(const int4*)(src + 32 * kvb + 8 * m);
        int sh = 16 * kvb + 4 * m;
        bits |= ((unsigned)(v.x != 0) << sh) | ((unsigned)(v.y != 0) << (sh + 1)) |
                ((unsigned)(v.z != 0) << (sh + 2)) | ((unsigned)(v.w != 0) << (sh + 3));
      }
    Mh[t] = bits;
  } else if (blk < 6144) {
    int t  = (blk - 2048) * 256 + threadIdx.x;
    int lq = t & 31, c = (t >> 5) & 15, kt = (t >> 9) & 31, bh = t >> 14;
    int kv = kt * 64 + (c >> 3) * 32 + lq;
    int d0 = ((c >> 1) & 3) * 16 + (c & 1) * 8;
    const float4* src = (const float4*)(K + ((size_t)bh * SEQ + kv) * DK + d0);
    float4 a = src[0], b4 = src[1];
    uint4 o = { pkrtz(a.x, a.y), pkrtz(a.z, a.w), pkrtz(b4.x, b4.y), pkrtz(b4.z, b4.w) };
    *(uint4*)(wsK + (size_t)t * 8) = o;
  } else {
    int t  = (blk - 6144) * 256 + threadIdx.x;
    int lq = t & 31, c = (t >> 5) & 15, kt = (t >> 9) & 31, bh = t >> 14;
    int kv0 = kt * 64 + ((c >> 1) & 3) * 16 + (c & 1) * 8;
    int d   = (c >> 3) * 32 + lq;
    const float* vp = V + ((size_t)bh * SEQ + kv0) * DK + d;
    float v[8];
#pragma unroll
    for (int j = 0; j < 8; ++j) v[j] = vp[(size_t)j * DK];
    uint4 o = { pkrtz(v[0], v[1]), pkrtz(v[2], v[3]), pkrtz(v[4], v[5]), pkrtz(v[6], v[7]) };
    *(uint4*)(wsV + (size_t)t * 8) = o;
  }
}

// ---- main attention kernel: 2 waves/block, kv-split x2, all-register --------

__global__ __launch_bounds__(128, 5) void sda_attn_kv2(
    const float* __restrict__ Q, const unsigned* __restrict__ Mh,
    const _Float16* __restrict__ wsK, const _Float16* __restrict__ wsV,
    float* __restrict__ O) {
  __shared__ float comb[64][36];   // wave-1 partials: 32 oacc f32 + lreg per lane

  // XCD swizzle: 4096 blocks, 8 XCDs -> XCD x gets blocks [x*512, x*512+512):
  // bh-major within an XCD -> 8 contiguous bh per XCD (K/V f16 = 4MB = L2)
  const int id = blockIdx.x;
  const int sw = (id & 7) * 512 + (id >> 3);
  const int bh = sw >> 6;          // 0..63
  const int qt = sw & 63;          // 0..63 (32 q-rows each)
  const int b  = bh >> 4;
  const int tid  = threadIdx.x;
  const int h    = tid >> 6;       // kv-half: 0 -> tiles 0..15, 1 -> tiles 16..31
  const int lane = tid & 63;
  const int lq   = lane & 31;
  const int hiL  = lane >> 5;

  const size_t base = (size_t)bh * SEQ * DK;
  const int    q    = qt * 32 + lq;

  // ---- Q B-frags: lane holds Q[q][kk*16 + hiL*8 + j], pre-scaled ----
  f16x8 qf[4];
  {
    const float* qp = Q + base + (size_t)q * DK + hiL * 8;
#pragma unroll
    for (int kk = 0; kk < 4; ++kk) {
      float4 A  = *(const float4*)(qp + kk * 16);
      float4 Bv = *(const float4*)(qp + kk * 16 + 4);
      uint4 u;
      u.x = pkrtz(A.x * QSCALE, A.y * QSCALE);
      u.y = pkrtz(A.z * QSCALE, A.w * QSCALE);
      u.z = pkrtz(Bv.x * QSCALE, Bv.y * QSCALE);
      u.w = pkrtz(Bv.z * QSCALE, Bv.w * QSCALE);
      qf[kk] = __builtin_bit_cast(f16x8, u);
    }
  }

  f32x16 oacc[2];
#pragma unroll
  for (int db = 0; db < 2; ++db)
#pragma unroll
    for (int r = 0; r < 16; ++r) oacc[db][r] = 0.f;
  float lreg = 0.f;

  // per-lane frag bases: tile kt block = 4096 f16; chunk c = 256 f16; elem = lq*8
  const _Float16* kp  = wsK + (size_t)bh * 32 * 4096 + (size_t)hiL * 256 + (size_t)lq * 8;
  const _Float16* vp  = wsV + (size_t)bh * 32 * 4096 + (size_t)hiL * 256 + (size_t)lq * 8;
  const unsigned* Mhp = Mh + ((size_t)b * SEQ + q) * 64 + hiL;

  f16x8 kfr[8], vfr[8];

#define LOADKF(t_)                                                        \
  {                                                                       \
    const _Float16* s_ = kp + (size_t)(t_) * 4096;                        \
    _Pragma("unroll") for (int kvb = 0; kvb < 2; ++kvb)                   \
      _Pragma("unroll") for (int kk = 0; kk < 4; ++kk)                    \
        kfr[kvb * 4 + kk] = *(const f16x8*)(s_ + kvb * 2048 + kk * 512);  \
  }
#define LOADVF(t_)                                                        \
  {                                                                       \
    const _Float16* s_ = vp + (size_t)(t_) * 4096;                        \
    _Pragma("unroll") for (int ks = 0; ks < 4; ++ks)                      \
      _Pragma("unroll") for (int db = 0; db < 2; ++db)                    \
        vfr[ks * 2 + db] = *(const f16x8*)(s_ + db * 2048 + ks * 512);    \
  }

  const f16x2v ones = {(_Float16)1.0f, (_Float16)1.0f};
  (void)ones;

  // ---- prologue (this wave's kv-half) ----
  const int t0 = h * (NT / 2), tEnd = t0 + (NT / 2);
  LOADKF(t0);
  LOADVF(t0);
  unsigned mw = Mhp[2 * t0];

  for (int t = t0; t < tEnd; ++t) {
    const int tn = (t + 1 < tEnd) ? t + 1 : t;   // last iter: harmless reload

    // ---- QK^T from registers ----
    f32x16 sc[2];
#pragma unroll
    for (int kvb = 0; kvb < 2; ++kvb)
#pragma unroll
      for (int r = 0; r < 16; ++r) sc[kvb][r] = 0.f;

    __builtin_amdgcn_s_setprio(1);
#pragma unroll
    for (int kk = 0; kk < 4; ++kk)
#pragma unroll
      for (int kvb = 0; kvb < 2; ++kvb)
        sc[kvb] = __builtin_amdgcn_mfma_f32_32x32x16_f16(kfr[kvb * 4 + kk], qf[kk],
                                                         sc[kvb], 0, 0, 0);
    __builtin_amdgcn_s_setprio(0);

    // ---- prefetch K(t+1) (lands during SM+PV) ----
    LOADKF(tn);
    unsigned mwn = Mhp[2 * tn];

    // ---- P = exp2(sc), mask-zero, pack f16; 2-chain fdot2 rowsum ----
    float rs0 = 0.f, rs1 = 0.f;
    unsigned pr[2][4][2];
#pragma unroll
    for (int kvb = 0; kvb < 2; ++kvb)
#pragma unroll
      for (int m = 0; m < 4; ++m) {
        float e0 = mzero(EXP2F(sc[kvb][4 * m + 0]), mw, 16 * kvb + 4 * m + 0);
        float e1 = mzero(EXP2F(sc[kvb][4 * m + 1]), mw, 16 * kvb + 4 * m + 1);
        float e2 = mzero(EXP2F(sc[kvb][4 * m + 2]), mw, 16 * kvb + 4 * m + 2);
        float e3 = mzero(EXP2F(sc[kvb][4 * m + 3]), mw, 16 * kvb + 4 * m + 3);
        unsigned w0 = pkrtz(e0, e1), w1 = pkrtz(e2, e3);
        pr[kvb][m][0] = w0;
        pr[kvb][m][1] = w1;
#if __has_builtin(__builtin_amdgcn_fdot2)
        rs0 = __builtin_amdgcn_fdot2(__builtin_bit_cast(f16x2v, w0), ones, rs0, false);
        rs1 = __builtin_amdgcn_fdot2(__builtin_bit_cast(f16x2v, w1), ones, rs1, false);
#else
        rs0 += e0 + e1;
        rs1 += e2 + e3;
#endif
      }
    {
      float rs = rs0 + rs1;
      unsigned ru = __builtin_bit_cast(unsigned, rs), plo, phi;
      halfswap(ru, ru, plo, phi, hiL);
      lreg += rs + __builtin_bit_cast(float, hiL ? plo : phi);
    }

    // ---- P exchange (permlane half-swap) + PV from registers ----
#pragma unroll
    for (int ks = 0; ks < 4; ++ks) {
      const int kvb = ks >> 1, ms = (ks & 1) * 2;
      unsigned w0, w1, w2, w3;
      halfswap(pr[kvb][ms][0], pr[kvb][ms + 1][0], w0, w2, hiL);
      halfswap(pr[kvb][ms][1], pr[kvb][ms + 1][1], w1, w3, hiL);
      f16x8 pf = __builtin_bit_cast(f16x8, make_uint4(w0, w1, w2, w3));

      __builtin_amdgcn_s_setprio(1);
#pragma unroll
      for (int db = 0; db < 2; ++db)
        oacc[db] = __builtin_amdgcn_mfma_f32_32x32x16_f16(vfr[ks * 2 + db], pf,
                                                          oacc[db], 0, 0, 0);
      __builtin_amdgcn_s_setprio(0);
    }

    // ---- prefetch V(t+1) ----
    LOADVF(tn);
    mw = mwn;
  }

  // ---- combine kv-halves through LDS (partials add; no rescale needed) ----
  if (h == 1) {
#pragma unroll
    for (int db = 0; db < 2; ++db)
#pragma unroll
      for (int m = 0; m < 4; ++m) {
        float4 o;
        o.x = oacc[db][4 * m + 0];
        o.y = oacc[db][4 * m + 1];
        o.z = oacc[db][4 * m + 2];
        o.w = oacc[db][4 * m + 3];
        *(float4*)&comb[lane][db * 16 + m * 4] = o;
      }
    comb[lane][32] = lreg;
  }
  __syncthreads();
  if (h == 0) {
#pragma unroll
    for (int db = 0; db < 2; ++db)
#pragma unroll
      for (int m = 0; m < 4; ++m) {
        float4 o = *(const float4*)&comb[lane][db * 16 + m * 4];
        oacc[db][4 * m + 0] += o.x;
        oacc[db][4 * m + 1] += o.y;
        oacc[db][4 * m + 2] += o.z;
        oacc[db][4 * m + 3] += o.w;
      }
    lreg += comb[lane][32];

    float inv = (lreg > 0.f) ? 1.0f / lreg : 0.f;
    float* op = O + base + (size_t)q * DK + 4 * hiL;
#pragma unroll
    for (int db = 0; db < 2; ++db)
#pragma unroll
      for (int m = 0; m < 4; ++m) {
        float4 o;
        o.x = oacc[db][4 * m + 0] * inv;
        o.y = oacc[db][4 * m + 1] * inv;
        o.z = oacc[db][4 * m + 2] * inv;
        o.w = oacc[db][4 * m + 3] * inv;
        *(float4*)(op + 32 * db + 8 * m) = o;
      }
  }
}

// ---- fallback (raw mask, in-kernel LDS staging; used only if ws too small) --

#define CH 264
#define QB 128
__global__ __launch_bounds__(256) void sda_attn_fb(
    const float* __restrict__ Q, const float* __restrict__ K,
    const float* __restrict__ V, const int* __restrict__ M,
    float* __restrict__ O) {
  __shared__ __align__(16) _Float16 Klf[2][16 * CH];
  __shared__ __align__(16) _Float16 Vtf[2][16 * CH];
  const int bh = blockIdx.x, qt = blockIdx.y, b = bh >> 4;
  const int tid = threadIdx.x, wid = tid >> 6, lane = tid & 63;
  const int lq = lane & 31, hiL = lane >> 5;
  const size_t base = (size_t)bh * SEQ * DK;
  const int q = qt * QB + wid * 32 + lq;

#define BARRIER()                                          \
  do {                                                     \
    asm volatile("s_waitcnt lgkmcnt(0)" ::: "memory");     \
    __builtin_amdgcn_s_barrier();                          \
  } while (0)

  f16x8 qf[4];
  {
    const float* qp = Q + base + (size_t)q * DK + hiL * 8;
#pragma unroll
    for (int kk = 0; kk < 4; ++kk) {
      float4 A = *(const float4*)(qp + kk * 16), Bv = *(const float4*)(qp + kk * 16 + 4);
      uint4 u = { pkrtz(A.x * QSCALE, A.y * QSCALE), pkrtz(A.z * QSCALE, A.w * QSCALE),
                  pkrtz(Bv.x * QSCALE, Bv.y * QSCALE), pkrtz(Bv.z * QSCALE, Bv.w * QSCALE) };
      qf[kk] = __builtin_bit_cast(f16x8, u);
    }
  }
  f32x16 oacc[2];
#pragma unroll
  for (int db = 0; db < 2; ++db)
#pragma unroll
    for (int r = 0; r < 16; ++r) oacc[db][r] = 0.f;
  float lreg = 0.f;

  const int krow = tid >> 2, c0 = tid & 3, kp = tid & 31, d8 = (tid >> 5) * 8;
  const float* Kg = K + base + (size_t)krow * DK + c0 * 16;
  const float* Vg0 = V + base + (size_t)(2 * kp) * DK + d8;
  const float* Vg1 = Vg0 + DK;
  const int kwa = ((krow >> 5) * 8 + c0 * 2) * CH + (krow & 31) * 8;
  const int kwb = kwa + CH;
  const int vwb = ((d8 >> 5) * 8 + (kp >> 3) * 2 + ((kp >> 2) & 1)) * CH +
                  (d8 & 31) * 8 + (kp & 3) * 2;
  float4 kpre[4], vpre[4];
#define FLOADT(kb_)                                                      \
  {                                                                      \
    const float* kg = Kg + (size_t)(kb_)*DK;                             \
    _Pragma("unroll") for (int i = 0; i < 4; ++i)                        \
        kpre[i] = *(const float4*)(kg + 4 * i);                          \
    const float* va = Vg0 + (size_t)(kb_)*DK;                            \
    const float* vb = Vg1 + (size_t)(kb_)*DK;                            \
    vpre[0] = *(const float4*)va; vpre[1] = *(const float4*)(va + 4);    \
    vpre[2] = *(const float4*)vb; vpre[3] = *(const float4*)(vb + 4);    \
  }
#define FSTAGE(b_)                                                          \
  {                                                                         \
    uint4 u0, u1;                                                           \
    u0.x = pkrtz(kpre[0].x, kpre[0].y); u0.y = pkrtz(kpre[0].z, kpre[0].w); \
    u0.z = pkrtz(kpre[1].x, kpre[1].y); u0.w = pkrtz(kpre[1].z, kpre[1].w); \
    u1.x = pkrtz(kpre[2].x, kpre[2].y); u1.y = pkrtz(kpre[2].z, kpre[2].w); \
    u1.z = pkrtz(kpre[3].x, kpre[3].y); u1.w = pkrtz(kpre[3].z, kpre[3].w); \
    *(uint4*)&Klf[b_][kwa] = u0;                                            \
    *(uint4*)&Klf[b_][kwb] = u1;                                            \
    const float* va_ = (const float*)&vpre[0];                              \
    const float* vc_ = (const float*)&vpre[2];                              \
    _Pragma("unroll") for (int j = 0; j < 8; ++j)                           \
        *(unsigned*)&Vtf[b_][vwb + j * 8] = pkrtz(va_[j], vc_[j]);          \
  }
  const int* Mrow = M + ((size_t)b * SEQ + q) * SEQ + 4 * hiL;
  FLOADT(0); FSTAGE(0); FLOADT(KVB);
  BARRIER();
  for (int t = 0; t < NT; ++t) {
    const int cur = t & 1;
    f32x16 sc[2];
#pragma unroll
    for (int kvb = 0; kvb < 2; ++kvb)
#pragma unroll
      for (int r = 0; r < 16; ++r) sc[kvb][r] = 0.f;
#pragma unroll
    for (int kk = 0; kk < 4; ++kk)
#pragma unroll
      for (int kvb = 0; kvb < 2; ++kvb) {
        f16x8 kf = *(const f16x8*)&Klf[cur][(kvb * 8 + kk * 2 + hiL) * CH + lq * 8];
        sc[kvb] = __builtin_amdgcn_mfma_f32_32x32x16_f16(kf, qf[kk], sc[kvb], 0, 0, 0);
      }
    const bool more = (t + 1 < NT);
    if (more) { FSTAGE(cur ^ 1); if (t + 2 < NT) FLOADT((t + 2) * KVB); }
    int4 mraw[8];
#pragma unroll
    for (int kvb = 0; kvb < 2; ++kvb)
#pragma unroll
      for (int m = 0; m < 4; ++m)
        mraw[kvb * 4 + m] = *(const int4*)(Mrow + t * KVB + 32 * kvb + 8 * m);
    float rs = 0.f;
    unsigned pr[2][4][2];
#pragma unroll
    for (int kvb = 0; kvb < 2; ++kvb) {
      float e[16];
#pragma unroll
      for (int r = 0; r < 16; ++r) {
        float ev = EXP2F(sc[kvb][r]);
        int4 v = mraw[kvb * 4 + (r >> 2)];
        int mm = (r & 3) == 0 ? v.x : (r & 3) == 1 ? v.y : (r & 3) == 2 ? v.z : v.w;
        ev = mm != 0 ? 0.f : ev;
        e[r] = ev; rs += ev;
      }
#pragma unroll
      for (int m = 0; m < 4; ++m) {
        pr[kvb][m][0] = pkrtz(e[4 * m + 0], e[4 * m + 1]);
        pr[kvb][m][1] = pkrtz(e[4 * m + 2], e[4 * m + 3]);
      }
    }
    {
      unsigned ru = __builtin_bit_cast(unsigned, rs), plo, phi;
      halfswap(ru, ru, plo, phi, hiL);
      lreg += rs + __builtin_bit_cast(float, hiL ? plo : phi);
    }
#pragma unroll
    for (int ks = 0; ks < 4; ++ks) {
      const int kvb = ks >> 1, ms = (ks & 1) * 2;
      unsigned w0, w1, w2, w3;
      halfswap(pr[kvb][ms][0], pr[kvb][ms + 1][0], w0, w2, hiL);
      halfswap(pr[kvb][ms][1], pr[kvb][ms + 1][1], w1, w3, hiL);
      f16x8 pf = __builtin_bit_cast(f16x8, make_uint4(w0, w1, w2, w3));
#pragma unroll
      for (int db = 0; db < 2; ++db) {
        f16x8 vf = *(const f16x8*)&Vtf[cur][(db * 8 + ks * 2 + hiL) * CH + lq * 8];
        oacc[db] = __builtin_amdgcn_mfma_f32_32x32x16_f16(vf, pf, oacc[db], 0, 0, 0);
      }
    }
    if (more) BARRIER();
  }
  float inv = (lreg > 0.f) ? 1.0f / lreg : 0.f;
  float* op = O + base + (size_t)q * DK + 4 * hiL;
#pragma unroll
  for (int db = 0; db < 2; ++db)
#pragma unroll
    for (int m = 0; m < 4; ++m) {
      float4 o;
      o.x = oacc[db][4 * m + 0] * inv;
      o.y = oacc[db][4 * m + 1] * inv;
      o.z = oacc[db][4 * m + 2] * inv;
      o.w = oacc[db][4 * m + 3] * inv;
      *(float4*)(op + 32 * db + 8 * m) = o;
    }
}

extern "C" void kernel_launch(void* const* d_in, const int* in_sizes, int n_in,
                              void* d_out, int out_size, void* d_ws, size_t ws_size,
                              hipStream_t stream) {
  const float* Q = (const float*)d_in[0];
  const float* K = (const float*)d_in[1];
  const float* V = (const float*)d_in[2];
  const int*   M = (const int*)d_in[3];
  float*       O = (float*)d_out;

  if (ws_size >= WS_NEED) {
    unsigned*  Mh  = (unsigned*)d_ws;
    _Float16*  wsK = (_Float16*)((char*)d_ws + WSK_OFF);
    _Float16*  wsV = (_Float16*)((char*)d_ws + WSV_OFF);
    pre_all<<<10240, 256, 0, stream>>>(M, K, V, Mh, wsK, wsV);
    sda_attn_kv2<<<NBH * 64, 128, 0, stream>>>(Q, Mh, wsK, wsV, O);
  } else {
    dim3 grid(NBH, SEQ / QB);
    sda_attn_fb<<<grid, 256, 0, stream>>>(Q, K, V, M, O);
  }
}

// Round 14
// 144.494 us; speedup vs baseline: 4.3641x; 4.3641x over previous
//
#include <hip/hip_runtime.h>
#include <hip/hip_bf16.h>

// ScaledDotAttention: B=4, H=16, S=2048, D=64, fp32 in/out, int mask (nonzero = masked out).
// R14: recombination of measured-best components. Attn loop = R8's (best profiled,
//      143.8us): dbuf LDS via global_load_lds from pre-relayouted f16 ws, post-exp
//      packed-bit masking, one vmcnt+barrier per tile. Pre = R9's single merged
//      dispatch. Plus two strict micro-wins: 2-op mzero mask (R10), 2-chain fdot2
//      rowsum (R9); QK in kvb-clusters so exp(sc0) overlaps sc1's MFMA tail.

#define SEQ   2048
#define DK    64
#define NB_   4
#define NBH   64
#define KVB   64
#define QB    128    // 4 waves x 32 q-rows
#define NT    (SEQ / KVB)

// ws layout: [0,2MB) packed mask | [2MB,18MB) K f16 chunks | [18MB,34MB) V^T f16 chunks
#define MASKH_WORDS ((size_t)NB_ * SEQ * 64)
#define WSK_OFF ((size_t)2 * 1024 * 1024)
#define WSV_OFF ((size_t)18 * 1024 * 1024)
#define WS_NEED ((size_t)34 * 1024 * 1024)

typedef float    f32x16 __attribute__((ext_vector_type(16)));
typedef _Float16 f16x8  __attribute__((ext_vector_type(8)));
typedef _Float16 f16x2v __attribute__((ext_vector_type(2)));

#define QSCALE 0.18033688011112042f   // log2(e)/sqrt(64): scores in log2 domain

#if __has_builtin(__builtin_amdgcn_exp2f)
#define EXP2F(x) __builtin_amdgcn_exp2f(x)
#else
__device__ __forceinline__ float EXP2F(float x) {
  float r;
  asm("v_exp_f32 %0, %1\n\ts_nop 1" : "=v"(r) : "v"(x));
  return r;
}
#endif

__device__ __forceinline__ unsigned pkrtz(float lo, float hi) {
  auto v = __builtin_amdgcn_cvt_pkrtz(lo, hi);
  return __builtin_bit_cast(unsigned, v);
}

// branchless mask-zero: keep v if bit idx of mw is 0 else +0.0f (2 ops)
__device__ __forceinline__ float mzero(float v, unsigned mw, int idx) {
  int s = ((int)(mw << (31 - idx))) >> 31;   // 0 or -1
  unsigned r = __builtin_bit_cast(unsigned, v) & ~(unsigned)s;
  return __builtin_bit_cast(float, r);
}

#define GLOAD16(g, l)                                                          \
  __builtin_amdgcn_global_load_lds(                                            \
      (const __attribute__((address_space(1))) unsigned*)(g),                  \
      (__attribute__((address_space(3))) unsigned*)(l), 16, 0, 0)

// lgkm-only barrier (keeps global_load_lds prefetch in flight)
#define BARRIER()                                          \
  do {                                                     \
    asm volatile("s_waitcnt lgkmcnt(0)" ::: "memory");     \
    __builtin_amdgcn_s_barrier();                          \
  } while (0)

__device__ __forceinline__ void halfswap(unsigned a, unsigned b,
                                         unsigned& out_lo, unsigned& out_hi, int hiL) {
#if __has_builtin(__builtin_amdgcn_permlane32_swap)
  auto r = __builtin_amdgcn_permlane32_swap(a, b, false, false);
  out_lo = r[0];
  out_hi = r[1];
#else
  unsigned ax = __shfl_xor(a, 32), bx = __shfl_xor(b, 32);
  out_lo = hiL ? bx : a;
  out_hi = hiL ? b : ax;
#endif
}

// ---- ONE merged pre-kernel (packed mask bits + K/V f16 relayout) ------------
// blocks [0,2048): packed mask bits, word (b,q,T,hi):
//   bit (16*kvb + 4*m + i) = mask[b][q][64T + 32kvb + 8m + 4hi + i]
// blocks [2048,6144): K -> f16 chunks (MFMA A-frag order)
// blocks [6144,10240): V -> f16 transposed chunks
__global__ __launch_bounds__(256) void pre_all(
    const int* __restrict__ M, const float* __restrict__ K,
    const float* __restrict__ V, unsigned* __restrict__ Mh,
    _Float16* __restrict__ wsK, _Float16* __restrict__ wsV) {
  const int blk = blockIdx.x;
  if (blk < 2048) {
    int t  = blk * 256 + threadIdx.x;
    int hi = t & 1, T = (t >> 1) & 31, q = (t >> 6) & 2047, b = t >> 17;
    const int* src = M + ((size_t)b * SEQ + q) * SEQ + T * 64 + 4 * hi;
    unsigned bits = 0;
#pragma unroll
    for (int kvb = 0; kvb < 2; ++kvb)
#pragma unroll
      for (int m = 0; m < 4; ++m) {
        int4 v = *(const int4*)(src + 32 * kvb + 8 * m);
        int sh = 16 * kvb + 4 * m;
        bits |= ((unsigned)(v.x != 0) << sh) | ((unsigned)(v.y != 0) << (sh + 1)) |
                ((unsigned)(v.z != 0) << (sh + 2)) | ((unsigned)(v.w != 0) << (sh + 3));
      }
    Mh[t] = bits;
  } else if (blk < 6144) {
    int t  = (blk - 2048) * 256 + threadIdx.x;
    int lq = t & 31, c = (t >> 5) & 15, kt = (t >> 9) & 31, bh = t >> 14;
    int kv = kt * 64 + (c >> 3) * 32 + lq;
    int d0 = ((c >> 1) & 3) * 16 + (c & 1) * 8;
    const float4* src = (const float4*)(K + ((size_t)bh * SEQ + kv) * DK + d0);
    float4 a = src[0], b4 = src[1];
    uint4 o = { pkrtz(a.x, a.y), pkrtz(a.z, a.w), pkrtz(b4.x, b4.y), pkrtz(b4.z, b4.w) };
    *(uint4*)(wsK + (size_t)t * 8) = o;
  } else {
    int t  = (blk - 6144) * 256 + threadIdx.x;
    int lq = t & 31, c = (t >> 5) & 15, kt = (t >> 9) & 31, bh = t >> 14;
    int kv0 = kt * 64 + ((c >> 1) & 3) * 16 + (c & 1) * 8;
    int d   = (c >> 3) * 32 + lq;
    const float* vp = V + ((size_t)bh * SEQ + kv0) * DK + d;
    float v[8];
#pragma unroll
    for (int j = 0; j < 8; ++j) v[j] = vp[(size_t)j * DK];
    uint4 o = { pkrtz(v[0], v[1]), pkrtz(v[2], v[3]), pkrtz(v[4], v[5]), pkrtz(v[6], v[7]) };
    *(uint4*)(wsV + (size_t)t * 8) = o;
  }
}

// ---- main attention kernel (R8 structure) -----------------------------------

__global__ __launch_bounds__(256) void sda_attn_pc(
    const float* __restrict__ Q, const unsigned* __restrict__ Mh,
    const _Float16* __restrict__ wsK, const _Float16* __restrict__ wsV,
    float* __restrict__ O) {
  // per buffer: 16 chunks x 32 lq x 8 f16 = 8 KB, linear (global_load_lds-friendly)
  __shared__ __align__(16) _Float16 Kl[2][16 * 256];
  __shared__ __align__(16) _Float16 Vt[2][16 * 256];

  const int bh   = blockIdx.x;
  const int qt   = blockIdx.y;
  const int b    = bh >> 4;
  const int tid  = threadIdx.x;
  const int wid  = tid >> 6;
  const int lane = tid & 63;
  const int lq   = lane & 31;
  const int hiL  = lane >> 5;

  const size_t base = (size_t)bh * SEQ * DK;
  const int    q    = qt * QB + wid * 32 + lq;

  // ---- Q B-frags: lane holds Q[q][kk*16 + hiL*8 + j], pre-scaled ----
  f16x8 qf[4];
  {
    const float* qp = Q + base + (size_t)q * DK + hiL * 8;
#pragma unroll
    for (int kk = 0; kk < 4; ++kk) {
      float4 A  = *(const float4*)(qp + kk * 16);
      float4 Bv = *(const float4*)(qp + kk * 16 + 4);
      uint4 u;
      u.x = pkrtz(A.x * QSCALE, A.y * QSCALE);
      u.y = pkrtz(A.z * QSCALE, A.w * QSCALE);
      u.z = pkrtz(Bv.x * QSCALE, Bv.y * QSCALE);
      u.w = pkrtz(Bv.z * QSCALE, Bv.w * QSCALE);
      qf[kk] = __builtin_bit_cast(f16x8, u);
    }
  }

  f32x16 oacc[2];
#pragma unroll
  for (int db = 0; db < 2; ++db)
#pragma unroll
    for (int r = 0; r < 16; ++r) oacc[db][r] = 0.f;
  float lreg = 0.f;

  // staging sources (tile block = 4096 f16, identical linear order to LDS)
  const _Float16* skb = wsK + (size_t)bh * 32 * 4096 + wid * 1024 + lane * 8;
  const _Float16* svb = wsV + (size_t)bh * 32 * 4096 + wid * 1024 + lane * 8;

#define STAGE_GL(buf_, kt_)                                   \
  {                                                           \
    const _Float16* sk = skb + (size_t)(kt_) * 4096;          \
    const _Float16* sv = svb + (size_t)(kt_) * 4096;          \
    _Float16* dk = &Kl[buf_][wid * 1024];                     \
    _Float16* dv = &Vt[buf_][wid * 1024];                     \
    GLOAD16(sk, dk); GLOAD16(sk + 512, dk + 512);             \
    GLOAD16(sv, dv); GLOAD16(sv + 512, dv + 512);             \
  }

  const unsigned* Mhp = Mh + ((size_t)b * SEQ + q) * 64 + hiL;
  const f16x2v ones = {(_Float16)1.0f, (_Float16)1.0f};
  (void)ones;

  // ---- prologue ----
  STAGE_GL(0, 0);
  unsigned mw_cur = Mhp[0];
  asm volatile("s_waitcnt vmcnt(0)" ::: "memory");
  BARRIER();

  for (int t = 0; t < NT; ++t) {
    const int  cur  = t & 1;
    const bool more = (t + 1 < NT);
    unsigned mw_next = 0;
    if (more) {
      STAGE_GL(cur ^ 1, t + 1);     // async into the buffer freed by last barrier
      mw_next = Mhp[2 * (t + 1)];
    }

    // ---- QK^T (swapped), kvb-clustered: sc0 completes first so its exp can
    //      overlap sc1's MFMA tail ----
    f32x16 sc0, sc1;
#pragma unroll
    for (int r = 0; r < 16; ++r) { sc0[r] = 0.f; sc1[r] = 0.f; }

    __builtin_amdgcn_s_setprio(1);
#pragma unroll
    for (int kk = 0; kk < 4; ++kk) {
      f16x8 kf = *(const f16x8*)&Kl[cur][(0 * 8 + kk * 2 + hiL) * 256 + lq * 8];
      sc0 = __builtin_amdgcn_mfma_f32_32x32x16_f16(kf, qf[kk], sc0, 0, 0, 0);
    }
#pragma unroll
    for (int kk = 0; kk < 4; ++kk) {
      f16x8 kf = *(const f16x8*)&Kl[cur][(1 * 8 + kk * 2 + hiL) * 256 + lq * 8];
      sc1 = __builtin_amdgcn_mfma_f32_32x32x16_f16(kf, qf[kk], sc1, 0, 0, 0);
    }
    __builtin_amdgcn_s_setprio(0);

    // ---- P = exp2(sc), 2-op mzero, pack f16; 2-chain fdot2 rowsum ----
    float rs0 = 0.f, rs1 = 0.f;
    unsigned pr[2][4][2];
#pragma unroll
    for (int m = 0; m < 4; ++m) {
      float e0 = mzero(EXP2F(sc0[4 * m + 0]), mw_cur, 4 * m + 0);
      float e1 = mzero(EXP2F(sc0[4 * m + 1]), mw_cur, 4 * m + 1);
      float e2 = mzero(EXP2F(sc0[4 * m + 2]), mw_cur, 4 * m + 2);
      float e3 = mzero(EXP2F(sc0[4 * m + 3]), mw_cur, 4 * m + 3);
      unsigned w0 = pkrtz(e0, e1), w1 = pkrtz(e2, e3);
      pr[0][m][0] = w0;
      pr[0][m][1] = w1;
#if __has_builtin(__builtin_amdgcn_fdot2)
      rs0 = __builtin_amdgcn_fdot2(__builtin_bit_cast(f16x2v, w0), ones, rs0, false);
      rs1 = __builtin_amdgcn_fdot2(__builtin_bit_cast(f16x2v, w1), ones, rs1, false);
#else
      rs0 += e0 + e1;
      rs1 += e2 + e3;
#endif
    }
#pragma unroll
    for (int m = 0; m < 4; ++m) {
      float e0 = mzero(EXP2F(sc1[4 * m + 0]), mw_cur, 16 + 4 * m + 0);
      float e1 = mzero(EXP2F(sc1[4 * m + 1]), mw_cur, 16 + 4 * m + 1);
      float e2 = mzero(EXP2F(sc1[4 * m + 2]), mw_cur, 16 + 4 * m + 2);
      float e3 = mzero(EXP2F(sc1[4 * m + 3]), mw_cur, 16 + 4 * m + 3);
      unsigned w0 = pkrtz(e0, e1), w1 = pkrtz(e2, e3);
      pr[1][m][0] = w0;
      pr[1][m][1] = w1;
#if __has_builtin(__builtin_amdgcn_fdot2)
      rs0 = __builtin_amdgcn_fdot2(__builtin_bit_cast(f16x2v, w0), ones, rs0, false);
      rs1 = __builtin_amdgcn_fdot2(__builtin_bit_cast(f16x2v, w1), ones, rs1, false);
#else
      rs0 += e0 + e1;
      rs1 += e2 + e3;
#endif
    }

    // cross-half row-sum
    {
      float rs = rs0 + rs1;
      unsigned ru = __builtin_bit_cast(unsigned, rs), plo, phi;
      halfswap(ru, ru, plo, phi, hiL);
      lreg += rs + __builtin_bit_cast(float, hiL ? plo : phi);
    }

    // ---- P exchange (permlane half-swap) + PV ----
#pragma unroll
    for (int ks = 0; ks < 4; ++ks) {
      const int kvb = ks >> 1, ms = (ks & 1) * 2;
      unsigned w0, w1, w2, w3;
      halfswap(pr[kvb][ms][0], pr[kvb][ms + 1][0], w0, w2, hiL);
      halfswap(pr[kvb][ms][1], pr[kvb][ms + 1][1], w1, w3, hiL);
      f16x8 pf = __builtin_bit_cast(f16x8, make_uint4(w0, w1, w2, w3));

      __builtin_amdgcn_s_setprio(1);
#pragma unroll
      for (int db = 0; db < 2; ++db) {
        f16x8 vf = *(const f16x8*)&Vt[cur][(db * 8 + ks * 2 + hiL) * 256 + lq * 8];
        oacc[db] = __builtin_amdgcn_mfma_f32_32x32x16_f16(vf, pf, oacc[db], 0, 0, 0);
      }
      __builtin_amdgcn_s_setprio(0);
    }

    mw_cur = mw_next;
    if (more) {
      asm volatile("s_waitcnt vmcnt(0)" ::: "memory");   // own 4 gloads landed
      BARRIER();                                          // all slices visible
    }
  }

  // ---- epilogue: oacc[db][r] = O^T[d = 32db + (r&3)+8(r>>2)+4hiL][q]; store O[q][d] ----
  float inv = (lreg > 0.f) ? 1.0f / lreg : 0.f;
  float* op = O + base + (size_t)q * DK + 4 * hiL;
#pragma unroll
  for (int db = 0; db < 2; ++db)
#pragma unroll
    for (int m = 0; m < 4; ++m) {
      float4 o;
      o.x = oacc[db][4 * m + 0] * inv;
      o.y = oacc[db][4 * m + 1] * inv;
      o.z = oacc[db][4 * m + 2] * inv;
      o.w = oacc[db][4 * m + 3] * inv;
      *(float4*)(op + 32 * db + 8 * m) = o;
    }
}

// ---- fallback (raw mask, in-kernel LDS staging; used only if ws too small) --

#define CH 264
__global__ __launch_bounds__(256) void sda_attn_fb(
    const float* __restrict__ Q, const float* __restrict__ K,
    const float* __restrict__ V, const int* __restrict__ M,
    float* __restrict__ O) {
  __shared__ __align__(16) _Float16 Klf[2][16 * CH];
  __shared__ __align__(16) _Float16 Vtf[2][16 * CH];
  const int bh = blockIdx.x, qt = blockIdx.y, b = bh >> 4;
  const int tid = threadIdx.x, wid = tid >> 6, lane = tid & 63;
  const int lq = lane & 31, hiL = lane >> 5;
  const size_t base = (size_t)bh * SEQ * DK;
  const int q = qt * QB + wid * 32 + lq;

  f16x8 qf[4];
  {
    const float* qp = Q + base + (size_t)q * DK + hiL * 8;
#pragma unroll
    for (int kk = 0; kk < 4; ++kk) {
      float4 A = *(const float4*)(qp + kk * 16), Bv = *(const float4*)(qp + kk * 16 + 4);
      uint4 u = { pkrtz(A.x * QSCALE, A.y * QSCALE), pkrtz(A.z * QSCALE, A.w * QSCALE),
                  pkrtz(Bv.x * QSCALE, Bv.y * QSCALE), pkrtz(Bv.z * QSCALE, Bv.w * QSCALE) };
      qf[kk] = __builtin_bit_cast(f16x8, u);
    }
  }
  f32x16 oacc[2];
#pragma unroll
  for (int db = 0; db < 2; ++db)
#pragma unroll
    for (int r = 0; r < 16; ++r) oacc[db][r] = 0.f;
  float lreg = 0.f;

  const int krow = tid >> 2, c0 = tid & 3, kp = tid & 31, d8 = (tid >> 5) * 8;
  const float* Kg = K + base + (size_t)krow * DK + c0 * 16;
  const float* Vg0 = V + base + (size_t)(2 * kp) * DK + d8;
  const float* Vg1 = Vg0 + DK;
  const int kwa = ((krow >> 5) * 8 + c0 * 2) * CH + (krow & 31) * 8;
  const int kwb = kwa + CH;
  const int vwb = ((d8 >> 5) * 8 + (kp >> 3) * 2 + ((kp >> 2) & 1)) * CH +
                  (d8 & 31) * 8 + (kp & 3) * 2;
  float4 kpre[4], vpre[4];
#define FLOADT(kb_)                                                      \
  {                                                                      \
    const float* kg = Kg + (size_t)(kb_)*DK;                             \
    _Pragma("unroll") for (int i = 0; i < 4; ++i)                        \
        kpre[i] = *(const float4*)(kg + 4 * i);                          \
    const float* va = Vg0 + (size_t)(kb_)*DK;                            \
    const float* vb = Vg1 + (size_t)(kb_)*DK;                            \
    vpre[0] = *(const float4*)va; vpre[1] = *(const float4*)(va + 4);    \
    vpre[2] = *(const float4*)vb; vpre[3] = *(const float4*)(vb + 4);    \
  }
#define FSTAGE(b_)                                                          \
  {                                                                         \
    uint4 u0, u1;                                                           \
    u0.x = pkrtz(kpre[0].x, kpre[0].y); u0.y = pkrtz(kpre[0].z, kpre[0].w); \
    u0.z = pkrtz(kpre[1].x, kpre[1].y); u0.w = pkrtz(kpre[1].z, kpre[1].w); \
    u1.x = pkrtz(kpre[2].x, kpre[2].y); u1.y = pkrtz(kpre[2].z, kpre[2].w); \
    u1.z = pkrtz(kpre[3].x, kpre[3].y); u1.w = pkrtz(kpre[3].z, kpre[3].w); \
    *(uint4*)&Klf[b_][kwa] = u0;                                            \
    *(uint4*)&Klf[b_][kwb] = u1;                                            \
    const float* va_ = (const float*)&vpre[0];                              \
    const float* vc_ = (const float*)&vpre[2];                              \
    _Pragma("unroll") for (int j = 0; j < 8; ++j)                           \
        *(unsigned*)&Vtf[b_][vwb + j * 8] = pkrtz(va_[j], vc_[j]);          \
  }
  const int* Mrow = M + ((size_t)b * SEQ + q) * SEQ + 4 * hiL;
  FLOADT(0); FSTAGE(0); FLOADT(KVB);
  BARRIER();
  for (int t = 0; t < NT; ++t) {
    const int cur = t & 1;
    f32x16 sc[2];
#pragma unroll
    for (int kvb = 0; kvb < 2; ++kvb)
#pragma unroll
      for (int r = 0; r < 16; ++r) sc[kvb][r] = 0.f;
#pragma unroll
    for (int kk = 0; kk < 4; ++kk)
#pragma unroll
      for (int kvb = 0; kvb < 2; ++kvb) {
        f16x8 kf = *(const f16x8*)&Klf[cur][(kvb * 8 + kk * 2 + hiL) * CH + lq * 8];
        sc[kvb] = __builtin_amdgcn_mfma_f32_32x32x16_f16(kf, qf[kk], sc[kvb], 0, 0, 0);
      }
    const bool more = (t + 1 < NT);
    if (more) { FSTAGE(cur ^ 1); if (t + 2 < NT) FLOADT((t + 2) * KVB); }
    int4 mraw[8];
#pragma unroll
    for (int kvb = 0; kvb < 2; ++kvb)
#pragma unroll
      for (int m = 0; m < 4; ++m)
        mraw[kvb * 4 + m] = *(const int4*)(Mrow + t * KVB + 32 * kvb + 8 * m);
    float rs = 0.f;
    unsigned pr[2][4][2];
#pragma unroll
    for (int kvb = 0; kvb < 2; ++kvb) {
      float e[16];
#pragma unroll
      for (int r = 0; r < 16; ++r) {
        float ev = EXP2F(sc[kvb][r]);
        int4 v = mraw[kvb * 4 + (r >> 2)];
        int mm = (r & 3) == 0 ? v.x : (r & 3) == 1 ? v.y : (r & 3) == 2 ? v.z : v.w;
        ev = mm != 0 ? 0.f : ev;
        e[r] = ev; rs += ev;
      }
#pragma unroll
      for (int m = 0; m < 4; ++m) {
        pr[kvb][m][0] = pkrtz(e[4 * m + 0], e[4 * m + 1]);
        pr[kvb][m][1] = pkrtz(e[4 * m + 2], e[4 * m + 3]);
      }
    }
    {
      unsigned ru = __builtin_bit_cast(unsigned, rs), plo, phi;
      halfswap(ru, ru, plo, phi, hiL);
      lreg += rs + __builtin_bit_cast(float, hiL ? plo : phi);
    }
#pragma unroll
    for (int ks = 0; ks < 4; ++ks) {
      const int kvb = ks >> 1, ms = (ks & 1) * 2;
      unsigned w0, w1, w2, w3;
      halfswap(pr[kvb][ms][0], pr[kvb][ms + 1][0], w0, w2, hiL);
      halfswap(pr[kvb][ms][1], pr[kvb][ms + 1][1], w1, w3, hiL);
      f16x8 pf = __builtin_bit_cast(f16x8, make_uint4(w0, w1, w2, w3));
#pragma unroll
      for (int db = 0; db < 2; ++db) {
        f16x8 vf = *(const f16x8*)&Vtf[cur][(db * 8 + ks * 2 + hiL) * CH + lq * 8];
        oacc[db] = __builtin_amdgcn_mfma_f32_32x32x16_f16(vf, pf, oacc[db], 0, 0, 0);
      }
    }
    if (more) BARRIER();
  }
  float inv = (lreg > 0.f) ? 1.0f / lreg : 0.f;
  float* op = O + base + (size_t)q * DK + 4 * hiL;
#pragma unroll
  for (int db = 0; db < 2; ++db)
#pragma unroll
    for (int m = 0; m < 4; ++m) {
      float4 o;
      o.x = oacc[db][4 * m + 0] * inv;
      o.y = oacc[db][4 * m + 1] * inv;
      o.z = oacc[db][4 * m + 2] * inv;
      o.w = oacc[db][4 * m + 3] * inv;
      *(float4*)(op + 32 * db + 8 * m) = o;
    }
}

extern "C" void kernel_launch(void* const* d_in, const int* in_sizes, int n_in,
                              void* d_out, int out_size, void* d_ws, size_t ws_size,
                              hipStream_t stream) {
  const float* Q = (const float*)d_in[0];
  const float* K = (const float*)d_in[1];
  const float* V = (const float*)d_in[2];
  const int*   M = (const int*)d_in[3];
  float*       O = (float*)d_out;
  dim3 grid(NBH, SEQ / QB);   // (64, 16)

  if (ws_size >= WS_NEED) {
    unsigned*  Mh  = (unsigned*)d_ws;
    _Float16*  wsK = (_Float16*)((char*)d_ws + WSK_OFF);
    _Float16*  wsV = (_Float16*)((char*)d_ws + WSV_OFF);
    pre_all<<<10240, 256, 0, stream>>>(M, K, V, Mh, wsK, wsV);
    sda_attn_pc<<<grid, 256, 0, stream>>>(Q, Mh, wsK, wsV, O);
  } else {
    sda_attn_fb<<<grid, 256, 0, stream>>>(Q, K, V, M, O);
  }
}